// Round 11
// baseline (56.863 us; speedup 1.0000x reference)
//
#include <hip/hip_runtime.h>
#include <hip/hip_bf16.h>

// Shapes
#define B_ 64
#define L_ 64
#define D_ 512
#define F_ 32
#define H_ 512
#define M_ROWS 2048
#define M2 2112
#define KA 1024

typedef __attribute__((ext_vector_type(8))) short bf16x8;
typedef __attribute__((ext_vector_type(4))) float f32x4;

__device__ __forceinline__ float leaky(float v) { return v > 0.0f ? v : 0.01f * v; }

__device__ __forceinline__ unsigned short f2bf(float v) {
  unsigned int b = __float_as_uint(v);
  unsigned int r = b + 0x7FFF + ((b >> 16) & 1);  // RNE
  return (unsigned short)(r >> 16);
}
__device__ __forceinline__ float bf2f(unsigned short h) {
  return __uint_as_float(((unsigned int)h) << 16);
}
__device__ __forceinline__ void cvt_store4(unsigned short* ph, unsigned short* pl, float4 v) {
  ushort4 h, l;
  h.x = f2bf(v.x); l.x = f2bf(v.x - bf2f(h.x));
  h.y = f2bf(v.y); l.y = f2bf(v.y - bf2f(h.y));
  h.z = f2bf(v.z); l.z = f2bf(v.z - bf2f(h.z));
  h.w = f2bf(v.w); l.w = f2bf(v.w - bf2f(h.w));
  *(ushort4*)ph = h;
  *(ushort4*)pl = l;
}

#define GLOAD16(GP, LP)                                              \
  __builtin_amdgcn_global_load_lds(                                  \
      (const __attribute__((address_space(1))) unsigned int*)(GP),   \
      (__attribute__((address_space(3))) unsigned int*)(LP), 16, 0, 0)

// ---------------- Kernel 1: fused prep (EXACT R7 version, grid 576) --------
__global__ __launch_bounds__(256) void prep(
    const float* __restrict__ x, const int* __restrict__ idx1,
    const int* __restrict__ idx2,
    const float* __restrict__ Ws0, const float* __restrict__ Wa0,
    const float* __restrict__ Ws1, const float* __restrict__ Wa1,
    unsigned short* __restrict__ Xhi, unsigned short* __restrict__ Xlo,
    unsigned short* __restrict__ Mh, unsigned short* __restrict__ Ml,
    unsigned short* __restrict__ W0thi, unsigned short* __restrict__ W0tlo,
    unsigned short* __restrict__ W1thi, unsigned short* __restrict__ W1tlo) {
  __shared__ __align__(16) char smem[33024];
  const int blk = blockIdx.x;
  const int t = threadIdx.x;

  if (blk < 64) {
    const int b = blk;
    const float* src = x + (size_t)b * (L_ * D_);
    unsigned short* dh = Xhi + (size_t)b * (L_ * D_);
    unsigned short* dl = Xlo + (size_t)b * (L_ * D_);
#pragma unroll 4
    for (int i = 0; i < 32; ++i) {
      const int f4 = t + 256 * i;
      const float4 v = *(const float4*)(src + (size_t)f4 * 4);
      cvt_store4(dh + (size_t)f4 * 4, dl + (size_t)f4 * 4, v);
    }
  } else if (blk < 320) {
    const int q = blk - 64;
    const int k0 = (q & 15) * 64;
    const int n0 = ((q >> 4) & 7) * 64;
    const int cat = q >> 7;
    float (*lt)[72] = (float(*)[72])smem;
    const float* src = (cat == 0)
        ? (k0 < 512 ? Ws0 + (size_t)k0 * H_ : Wa0 + (size_t)(k0 - 512) * H_)
        : (k0 < 512 ? Ws1 + (size_t)k0 * H_ : Wa1 + (size_t)(k0 - 512) * H_);
    unsigned short* dhi = (cat == 0) ? W0thi : W1thi;
    unsigned short* dlo = (cat == 0) ? W0tlo : W1tlo;
#pragma unroll
    for (int i = 0; i < 4; ++i) {
      const int idx4 = t + 256 * i;
      const int kl = idx4 >> 4;
      const int n4 = (idx4 & 15) * 4;
      *(float4*)&lt[kl][n4] = *(const float4*)(src + (size_t)kl * H_ + n0 + n4);
    }
    __syncthreads();
#pragma unroll
    for (int i = 0; i < 4; ++i) {
      const int idx4 = t + 256 * i;
      const int nl = idx4 >> 4;
      const int k4 = (idx4 & 15) * 4;
      ushort4 h, l;
      const float v0 = lt[k4 + 0][nl], v1 = lt[k4 + 1][nl];
      const float v2 = lt[k4 + 2][nl], v3 = lt[k4 + 3][nl];
      h.x = f2bf(v0); l.x = f2bf(v0 - bf2f(h.x));
      h.y = f2bf(v1); l.y = f2bf(v1 - bf2f(h.y));
      h.z = f2bf(v2); l.z = f2bf(v2 - bf2f(h.z));
      h.w = f2bf(v3); l.w = f2bf(v3 - bf2f(h.w));
      *(ushort4*)(dhi + (size_t)(n0 + nl) * KA + k0 + k4) = h;
      *(ushort4*)(dlo + (size_t)(n0 + nl) * KA + k0 + k4) = l;
    }
  } else {
    const int q = blk - 320;
    const int b = q >> 2;
    const int nt0 = (q & 3) * 2;
    unsigned int* cnt = (unsigned int*)smem;               // [33][64]
    unsigned short* Cm = (unsigned short*)(smem + 8448);   // [48][64]
    unsigned short* XTh = (unsigned short*)(smem + 14592); // [64][72]
    unsigned short* XTl = XTh + 64 * 72;
    const int lane = t & 63;
    const int w = t >> 6;
    const int lr = lane & 15;
    const int kb8 = (lane >> 4) * 8;

#pragma unroll
    for (int i = 0; i < 9; ++i) { const int p = t + 256 * i; if (p < 2112) cnt[p] = 0u; }
#pragma unroll
    for (int i = 0; i < 12; ++i) Cm[t + 256 * i] = 0;
    __syncthreads();
#pragma unroll
    for (int i = 0; i < 4; ++i) {
      const int j = t + 256 * i;
      atomicAdd(&cnt[(j >> 5) * 64 + idx2[(size_t)b * 1024 + j]], 1u);
    }
    if (t < 32) atomicAdd(&cnt[32 * 64 + idx1[b * F_ + t]], 1u);
    __syncthreads();
#pragma unroll
    for (int i = 0; i < 9; ++i) {
      const int p = t + 256 * i;
      if (p < 2112) Cm[p] = f2bf((float)cnt[p] * 0.03125f);
    }
    __syncthreads();
    bf16x8 Af[3][2];
#pragma unroll
    for (int mi = 0; mi < 3; ++mi)
#pragma unroll
      for (int kt = 0; kt < 2; ++kt)
        Af[mi][kt] = *(const bf16x8*)&Cm[(mi * 16 + lr) * 64 + kt * 32 + kb8];

#pragma unroll
    for (int tt = 0; tt < 2; ++tt) {
      const int nbase = (nt0 + tt) * 64;
#pragma unroll
      for (int i = 0; i < 4; ++i) {
        const int f4 = t + 256 * i;
        const int l = f4 >> 4;
        const int c4 = (f4 & 15) * 4;
        const float4 v = *(const float4*)(x + (size_t)b * (L_ * D_) + (size_t)l * D_ + nbase + c4);
        unsigned short h;
        h = f2bf(v.x); XTh[(c4 + 0) * 72 + l] = h; XTl[(c4 + 0) * 72 + l] = f2bf(v.x - bf2f(h));
        h = f2bf(v.y); XTh[(c4 + 1) * 72 + l] = h; XTl[(c4 + 1) * 72 + l] = f2bf(v.y - bf2f(h));
        h = f2bf(v.z); XTh[(c4 + 2) * 72 + l] = h; XTl[(c4 + 2) * 72 + l] = f2bf(v.z - bf2f(h));
        h = f2bf(v.w); XTh[(c4 + 3) * 72 + l] = h; XTl[(c4 + 3) * 72 + l] = f2bf(v.w - bf2f(h));
      }
      __syncthreads();
      f32x4 acc[3] = {};
#pragma unroll
      for (int kt = 0; kt < 2; ++kt) {
        const bf16x8 Bh = *(const bf16x8*)&XTh[(w * 16 + lr) * 72 + kt * 32 + kb8];
        const bf16x8 Bl = *(const bf16x8*)&XTl[(w * 16 + lr) * 72 + kt * 32 + kb8];
#pragma unroll
        for (int mi = 0; mi < 3; ++mi) {
          acc[mi] = __builtin_amdgcn_mfma_f32_16x16x32_bf16(Af[mi][kt], Bh, acc[mi], 0, 0, 0);
          acc[mi] = __builtin_amdgcn_mfma_f32_16x16x32_bf16(Af[mi][kt], Bl, acc[mi], 0, 0, 0);
        }
      }
      const int col = nbase + w * 16 + lr;
#pragma unroll
      for (int mi = 0; mi < 3; ++mi)
#pragma unroll
        for (int r = 0; r < 4; ++r) {
          const int row48 = mi * 16 + (lane >> 4) * 4 + r;
          if (row48 > 32) continue;
          const size_t Mrow = (row48 < 32) ? (size_t)(b * F_ + row48) : (size_t)(M_ROWS + b);
          const float v = acc[mi][r];
          const unsigned short h = f2bf(v);
          Mh[Mrow * 512 + col] = h;
          Ml[Mrow * 512 + col] = f2bf(v - bf2f(h));
        }
      __syncthreads();
    }
  }
}

// ---------------- Kernel 2: barrier-light MFMA GEMM -------------------------
// BM=64 (4 waves x 16 rows), BN=32, K=1024 in 2 chunks of 512.
// A-frags: per-lane DIRECT global loads (natural gather via idx1, row=lane&15).
// W: LDS 64KB single-buffer per 512-k chunk, XOR-swizzled, 4 barriers/block.
// grid 528 XCD-chunk-swizzled. Fused bias+leaky+mean epilogue.
__global__ __launch_bounds__(256) void gemm1(
    const unsigned short* __restrict__ Xhi, const unsigned short* __restrict__ Xlo,
    const unsigned short* __restrict__ Mh, const unsigned short* __restrict__ Ml,
    const unsigned short* __restrict__ Wthi, const unsigned short* __restrict__ Wtlo,
    const int* __restrict__ idx1, const float* __restrict__ b0,
    unsigned short* __restrict__ Hhi, unsigned short* __restrict__ Hlo) {
  __shared__ __align__(16) unsigned short lds[32768];  // [2 pl][32 r][512 k]
  const int tid = threadIdx.x;
  const int lane = tid & 63;
  const int w = tid >> 6;       // wave = m-quarter (16 rows)
  const int lr = lane & 15;
  const int kq = lane >> 4;     // 0..3

  const int o = blockIdx.x;
  const int s = (o & 7) * 66 + (o >> 3);  // 528 = 8 XCDs * 66, bijective
  const int bmi = s >> 4;                 // 0..32
  const int bni = s & 15;
  const int bm = bmi * 64;
  const int bn = bni * 32;

  // per-lane A row (A-frag mapping: lane holds row lane&15, k-chunk (lane>>4)*8)
  const int R = bm + w * 16 + lr;
  const int xr = (bmi < 32) ? ((R >> 5) * 64 + idx1[R]) : ((R - M_ROWS) * 64);
  const unsigned short* aXh = Xhi + (size_t)xr * 512 + kq * 8;
  const unsigned short* aXl = Xlo + (size_t)xr * 512 + kq * 8;
  const unsigned short* aMh = Mh + (size_t)R * 512 + kq * 8;
  const unsigned short* aMl = Ml + (size_t)R * 512 + kq * 8;

  f32x4 accHH[2] = {};
  f32x4 accX[2] = {};

  for (int c = 0; c < 2; ++c) {
    // stage W chunk c: 64KB, dest linear, source pre-XOR-swizzled (rule #21)
#pragma unroll
    for (int i = 0; i < 16; ++i) {
      const int slot = (w * 16 + i) * 64 + lane;  // 0..4095 (16B slots)
      const int pl = slot >> 11;
      const int row = (slot >> 6) & 31;
      const int cb = slot & 63;
      const unsigned short* gp = (pl ? Wtlo : Wthi) +
          (size_t)(bn + row) * KA + c * 512 + ((cb ^ (row & 7)) * 8);
      GLOAD16(gp, &lds[(w * 16 + i) * 512]);
    }
    __syncthreads();  // staging landed (vmcnt drained by barrier)

    const unsigned short* ah = (c == 0) ? aXh : aMh;
    const unsigned short* al = (c == 0) ? aXl : aMl;

    bf16x8 Ah = *(const bf16x8*)(ah);
    bf16x8 Al = *(const bf16x8*)(al);
#pragma unroll
    for (int ks = 0; ks < 16; ++ks) {
      const int nk = (ks + 1) & 15;  // depth-1 A prefetch
      const bf16x8 AhN = *(const bf16x8*)(ah + nk * 32);
      const bf16x8 AlN = *(const bf16x8*)(al + nk * 32);
#pragma unroll
      for (int nf = 0; nf < 2; ++nf) {
        const int row = nf * 16 + lr;
        const int cbX = (ks * 4 + kq) ^ (row & 7);
        const bf16x8 Bh = *(const bf16x8*)&lds[row * 512 + cbX * 8];
        const bf16x8 Bl = *(const bf16x8*)&lds[16384 + row * 512 + cbX * 8];
        accHH[nf] = __builtin_amdgcn_mfma_f32_16x16x32_bf16(Ah, Bh, accHH[nf], 0, 0, 0);
        accX[nf]  = __builtin_amdgcn_mfma_f32_16x16x32_bf16(Ah, Bl, accX[nf], 0, 0, 0);
        accX[nf]  = __builtin_amdgcn_mfma_f32_16x16x32_bf16(Al, Bh, accX[nf], 0, 0, 0);
      }
      Ah = AhN;
      Al = AlN;
    }
    __syncthreads();  // protect LDS overwrite by next chunk / epilogue reuse
  }

  f32x4 acc[2];
  acc[0] = accHH[0] + accX[0];
  acc[1] = accHH[1] + accX[1];

  // Epilogue. C/D layout: col = lane&15, row = (lane>>4)*4 + reg.
  if (bmi < 32) {
    // wave w covers rows R=bm+w*16..+15 -> b = bmi*2 + (w>>1), f-half = (w&1)*16..
    float* P = (float*)lds;  // [4][32], reuse after final barrier
#pragma unroll
    for (int nf = 0; nf < 2; ++nf) {
      const int col = bn + nf * 16 + lr;
      const float bias = b0[col];
      float sv = 0.f;
#pragma unroll
      for (int r = 0; r < 4; ++r) sv += leaky(acc[nf][r] + bias);
      sv += __shfl_xor(sv, 16);
      sv += __shfl_xor(sv, 32);
      if (lane < 16) P[w * 32 + nf * 16 + lane] = sv;
    }
    __syncthreads();
    if (tid < 64) {
      const int half = tid >> 5;  // 0 -> waves 0+1 (b even), 1 -> waves 2+3
      const int col = tid & 31;
      const int b = bmi * 2 + half;
      const float sv = (P[(half * 2) * 32 + col] + P[(half * 2 + 1) * 32 + col]) * (1.0f / 32.0f);
      const unsigned short h = f2bf(sv);
      Hhi[(size_t)b * KA + 512 + bn + col] = h;
      Hlo[(size_t)b * KA + 512 + bn + col] = f2bf(sv - bf2f(h));
    }
  } else {
    // h0 rows: bb = R - 2048 = w*16 + (kq*4 + r)
#pragma unroll
    for (int nf = 0; nf < 2; ++nf) {
      const int col = bn + nf * 16 + lr;
      const float bias = b0[col];
#pragma unroll
      for (int r = 0; r < 4; ++r) {
        const int bb = w * 16 + kq * 4 + r;
        const float v = leaky(acc[nf][r] + bias);
        const unsigned short h = f2bf(v);
        Hhi[(size_t)bb * KA + col] = h;
        Hlo[(size_t)bb * KA + col] = f2bf(v - bf2f(h));
      }
    }
  }
}

// ---------------- Kernel 3: gemm2 split-K partials (EXACT R7) ---------------
__global__ __launch_bounds__(256) void gemm2(
    const unsigned short* __restrict__ Hhi, const unsigned short* __restrict__ Hlo,
    const unsigned short* __restrict__ Wthi, const unsigned short* __restrict__ Wtlo,
    float* __restrict__ part) {
  __shared__ float sacc[256][17];
  const int tid = threadIdx.x;
  const int w = tid >> 6;
  const int lane = tid & 63;
  const int lr = lane & 15;
  const int kb = lane >> 4;
  const int n0 = blockIdx.x * 16;
  const int kc = blockIdx.y * 128;

  f32x4 acc[4] = {};
  const int k = kc + w * 32 + kb * 8;
  const bf16x8 Bh = *(const bf16x8*)(Wthi + (size_t)(n0 + lr) * KA + k);
  const bf16x8 Bl = *(const bf16x8*)(Wtlo + (size_t)(n0 + lr) * KA + k);
#pragma unroll
  for (int mi = 0; mi < 4; ++mi) {
    const bf16x8 Ah = *(const bf16x8*)(Hhi + (size_t)(mi * 16 + lr) * KA + k);
    const bf16x8 Al = *(const bf16x8*)(Hlo + (size_t)(mi * 16 + lr) * KA + k);
    acc[mi] = __builtin_amdgcn_mfma_f32_16x16x32_bf16(Ah, Bh, acc[mi], 0, 0, 0);
    acc[mi] = __builtin_amdgcn_mfma_f32_16x16x32_bf16(Ah, Bl, acc[mi], 0, 0, 0);
    acc[mi] = __builtin_amdgcn_mfma_f32_16x16x32_bf16(Al, Bh, acc[mi], 0, 0, 0);
  }
#pragma unroll
  for (int mi = 0; mi < 4; ++mi)
#pragma unroll
    for (int r = 0; r < 4; ++r)
      sacc[((w * 4 + mi) * 4 + kb) * 4 + r][lr] = acc[mi][r];
  __syncthreads();

  const int lr2 = tid & 15;
  const int rg = tid >> 4;
  float* pp = part + (size_t)blockIdx.y * (B_ * H_);
#pragma unroll
  for (int q = 0; q < 4; ++q) {
    const int row = rg * 4 + q;
    const int mi = row >> 4, kb2 = (row >> 2) & 3, r = row & 3;
    float sv = 0.f;
#pragma unroll
    for (int w2 = 0; w2 < 4; ++w2)
      sv += sacc[((w2 * 4 + mi) * 4 + kb2) * 4 + r][lr2];
    pp[(size_t)row * H_ + n0 + lr2] = sv;
  }
}

// ---------------- Kernel 4: out = sum_k part + b1 (EXACT R7) ----------------
__global__ __launch_bounds__(256) void reduce_out(
    const float* __restrict__ part, const float* __restrict__ b1,
    float* __restrict__ out) {
  const int idx = blockIdx.x * 256 + threadIdx.x;
  const int c4 = (idx & 127) * 4;
  const size_t off = (size_t)(idx >> 7) * H_ + c4;
  float4 s = *(const float4*)(b1 + c4);
#pragma unroll
  for (int ky = 0; ky < 8; ++ky) {
    const float4 p = *(const float4*)(part + (size_t)ky * (B_ * H_) + off);
    s.x += p.x; s.y += p.y; s.z += p.z; s.w += p.w;
  }
  *(float4*)(out + off) = s;
}

extern "C" void kernel_launch(void* const* d_in, const int* in_sizes, int n_in,
                              void* d_out, int out_size, void* d_ws, size_t ws_size,
                              hipStream_t stream) {
  const float* x    = (const float*)d_in[0];
  const int*   idx1 = (const int*)d_in[1];
  const int*   idx2 = (const int*)d_in[2];
  const float* Wa0  = (const float*)d_in[3];
  const float* b0   = (const float*)d_in[4];
  const float* Ws0  = (const float*)d_in[5];
  const float* Wa1  = (const float*)d_in[6];
  const float* b1   = (const float*)d_in[7];
  const float* Ws1  = (const float*)d_in[8];
  float* out = (float*)d_out;

  unsigned short* wsu = (unsigned short*)d_ws;
  unsigned short* Xhi   = wsu;                          // 4096*512
  unsigned short* Xlo   = Xhi + (size_t)4096 * 512;
  unsigned short* Mh    = Xlo + (size_t)4096 * 512;     // 2112*512
  unsigned short* Ml    = Mh + (size_t)M2 * 512;
  unsigned short* W0thi = Ml + (size_t)M2 * 512;        // [512][1024] each
  unsigned short* W0tlo = W0thi + (size_t)H_ * KA;
  unsigned short* W1thi = W0tlo + (size_t)H_ * KA;
  unsigned short* W1tlo = W1thi + (size_t)H_ * KA;
  unsigned short* Hhi   = W1tlo + (size_t)H_ * KA;      // 64*1024 each
  unsigned short* Hlo   = Hhi + (size_t)B_ * KA;
  float* part = (float*)(Hlo + (size_t)B_ * KA);        // 8*64*512 fp32

  prep<<<576, 256, 0, stream>>>(x, idx1, idx2, Ws0, Wa0, Ws1, Wa1,
                                Xhi, Xlo, Mh, Ml, W0thi, W0tlo, W1thi, W1tlo);
  gemm1<<<528, 256, 0, stream>>>(Xhi, Xlo, Mh, Ml, W0thi, W0tlo,
                                 idx1, b0, Hhi, Hlo);
  gemm2<<<dim3(32, 8), 256, 0, stream>>>(Hhi, Hlo, W1thi, W1tlo, part);
  reduce_out<<<32, 256, 0, stream>>>(part, b1, out);
}

// Round 12
// 46.526 us; speedup vs baseline: 1.2222x; 1.2222x over previous
//
#include <hip/hip_runtime.h>
#include <hip/hip_bf16.h>

// Shapes
#define B_ 64
#define L_ 64
#define D_ 512
#define F_ 32
#define H_ 512
#define M_ROWS 2048
#define M2 2112
#define KA 1024

typedef __attribute__((ext_vector_type(8))) short bf16x8;
typedef __attribute__((ext_vector_type(4))) float f32x4;

__device__ __forceinline__ float leaky(float v) { return v > 0.0f ? v : 0.01f * v; }

__device__ __forceinline__ unsigned short f2bf(float v) {
  unsigned int b = __float_as_uint(v);
  unsigned int r = b + 0x7FFF + ((b >> 16) & 1);  // RNE
  return (unsigned short)(r >> 16);
}
__device__ __forceinline__ float bf2f(unsigned short h) {
  return __uint_as_float(((unsigned int)h) << 16);
}
__device__ __forceinline__ void cvt_store4(unsigned short* ph, unsigned short* pl, float4 v) {
  ushort4 h, l;
  h.x = f2bf(v.x); l.x = f2bf(v.x - bf2f(h.x));
  h.y = f2bf(v.y); l.y = f2bf(v.y - bf2f(h.y));
  h.z = f2bf(v.z); l.z = f2bf(v.z - bf2f(h.z));
  h.w = f2bf(v.w); l.w = f2bf(v.w - bf2f(h.w));
  *(ushort4*)ph = h;
  *(ushort4*)pl = l;
}

#define GLOAD16(GP, LP)                                              \
  __builtin_amdgcn_global_load_lds(                                  \
      (const __attribute__((address_space(1))) unsigned int*)(GP),   \
      (__attribute__((address_space(3))) unsigned int*)(LP), 16, 0, 0)

// ---------------- Kernel 1: fused prep (EXACT R7) ----------------
__global__ __launch_bounds__(256) void prep(
    const float* __restrict__ x, const int* __restrict__ idx1,
    const int* __restrict__ idx2,
    const float* __restrict__ Ws0, const float* __restrict__ Wa0,
    const float* __restrict__ Ws1, const float* __restrict__ Wa1,
    unsigned short* __restrict__ Xhi, unsigned short* __restrict__ Xlo,
    unsigned short* __restrict__ Mh, unsigned short* __restrict__ Ml,
    unsigned short* __restrict__ W0thi, unsigned short* __restrict__ W0tlo,
    unsigned short* __restrict__ W1thi, unsigned short* __restrict__ W1tlo) {
  __shared__ __align__(16) char smem[33024];
  const int blk = blockIdx.x;
  const int t = threadIdx.x;

  if (blk < 64) {
    const int b = blk;
    const float* src = x + (size_t)b * (L_ * D_);
    unsigned short* dh = Xhi + (size_t)b * (L_ * D_);
    unsigned short* dl = Xlo + (size_t)b * (L_ * D_);
#pragma unroll 4
    for (int i = 0; i < 32; ++i) {
      const int f4 = t + 256 * i;
      const float4 v = *(const float4*)(src + (size_t)f4 * 4);
      cvt_store4(dh + (size_t)f4 * 4, dl + (size_t)f4 * 4, v);
    }
  } else if (blk < 320) {
    const int q = blk - 64;
    const int k0 = (q & 15) * 64;
    const int n0 = ((q >> 4) & 7) * 64;
    const int cat = q >> 7;
    float (*lt)[72] = (float(*)[72])smem;
    const float* src = (cat == 0)
        ? (k0 < 512 ? Ws0 + (size_t)k0 * H_ : Wa0 + (size_t)(k0 - 512) * H_)
        : (k0 < 512 ? Ws1 + (size_t)k0 * H_ : Wa1 + (size_t)(k0 - 512) * H_);
    unsigned short* dhi = (cat == 0) ? W0thi : W1thi;
    unsigned short* dlo = (cat == 0) ? W0tlo : W1tlo;
#pragma unroll
    for (int i = 0; i < 4; ++i) {
      const int idx4 = t + 256 * i;
      const int kl = idx4 >> 4;
      const int n4 = (idx4 & 15) * 4;
      *(float4*)&lt[kl][n4] = *(const float4*)(src + (size_t)kl * H_ + n0 + n4);
    }
    __syncthreads();
#pragma unroll
    for (int i = 0; i < 4; ++i) {
      const int idx4 = t + 256 * i;
      const int nl = idx4 >> 4;
      const int k4 = (idx4 & 15) * 4;
      ushort4 h, l;
      const float v0 = lt[k4 + 0][nl], v1 = lt[k4 + 1][nl];
      const float v2 = lt[k4 + 2][nl], v3 = lt[k4 + 3][nl];
      h.x = f2bf(v0); l.x = f2bf(v0 - bf2f(h.x));
      h.y = f2bf(v1); l.y = f2bf(v1 - bf2f(h.y));
      h.z = f2bf(v2); l.z = f2bf(v2 - bf2f(h.z));
      h.w = f2bf(v3); l.w = f2bf(v3 - bf2f(h.w));
      *(ushort4*)(dhi + (size_t)(n0 + nl) * KA + k0 + k4) = h;
      *(ushort4*)(dlo + (size_t)(n0 + nl) * KA + k0 + k4) = l;
    }
  } else {
    const int q = blk - 320;
    const int b = q >> 2;
    const int nt0 = (q & 3) * 2;
    unsigned int* cnt = (unsigned int*)smem;               // [33][64]
    unsigned short* Cm = (unsigned short*)(smem + 8448);   // [48][64]
    unsigned short* XTh = (unsigned short*)(smem + 14592); // [64][72]
    unsigned short* XTl = XTh + 64 * 72;
    const int lane = t & 63;
    const int w = t >> 6;
    const int lr = lane & 15;
    const int kb8 = (lane >> 4) * 8;

#pragma unroll
    for (int i = 0; i < 9; ++i) { const int p = t + 256 * i; if (p < 2112) cnt[p] = 0u; }
#pragma unroll
    for (int i = 0; i < 12; ++i) Cm[t + 256 * i] = 0;
    __syncthreads();
#pragma unroll
    for (int i = 0; i < 4; ++i) {
      const int j = t + 256 * i;
      atomicAdd(&cnt[(j >> 5) * 64 + idx2[(size_t)b * 1024 + j]], 1u);
    }
    if (t < 32) atomicAdd(&cnt[32 * 64 + idx1[b * F_ + t]], 1u);
    __syncthreads();
#pragma unroll
    for (int i = 0; i < 9; ++i) {
      const int p = t + 256 * i;
      if (p < 2112) Cm[p] = f2bf((float)cnt[p] * 0.03125f);
    }
    __syncthreads();
    bf16x8 Af[3][2];
#pragma unroll
    for (int mi = 0; mi < 3; ++mi)
#pragma unroll
      for (int kt = 0; kt < 2; ++kt)
        Af[mi][kt] = *(const bf16x8*)&Cm[(mi * 16 + lr) * 64 + kt * 32 + kb8];

#pragma unroll
    for (int tt = 0; tt < 2; ++tt) {
      const int nbase = (nt0 + tt) * 64;
#pragma unroll
      for (int i = 0; i < 4; ++i) {
        const int f4 = t + 256 * i;
        const int l = f4 >> 4;
        const int c4 = (f4 & 15) * 4;
        const float4 v = *(const float4*)(x + (size_t)b * (L_ * D_) + (size_t)l * D_ + nbase + c4);
        unsigned short h;
        h = f2bf(v.x); XTh[(c4 + 0) * 72 + l] = h; XTl[(c4 + 0) * 72 + l] = f2bf(v.x - bf2f(h));
        h = f2bf(v.y); XTh[(c4 + 1) * 72 + l] = h; XTl[(c4 + 1) * 72 + l] = f2bf(v.y - bf2f(h));
        h = f2bf(v.z); XTh[(c4 + 2) * 72 + l] = h; XTl[(c4 + 2) * 72 + l] = f2bf(v.z - bf2f(h));
        h = f2bf(v.w); XTh[(c4 + 3) * 72 + l] = h; XTl[(c4 + 3) * 72 + l] = f2bf(v.w - bf2f(h));
      }
      __syncthreads();
      f32x4 acc[3] = {};
#pragma unroll
      for (int kt = 0; kt < 2; ++kt) {
        const bf16x8 Bh = *(const bf16x8*)&XTh[(w * 16 + lr) * 72 + kt * 32 + kb8];
        const bf16x8 Bl = *(const bf16x8*)&XTl[(w * 16 + lr) * 72 + kt * 32 + kb8];
#pragma unroll
        for (int mi = 0; mi < 3; ++mi) {
          acc[mi] = __builtin_amdgcn_mfma_f32_16x16x32_bf16(Af[mi][kt], Bh, acc[mi], 0, 0, 0);
          acc[mi] = __builtin_amdgcn_mfma_f32_16x16x32_bf16(Af[mi][kt], Bl, acc[mi], 0, 0, 0);
        }
      }
      const int col = nbase + w * 16 + lr;
#pragma unroll
      for (int mi = 0; mi < 3; ++mi)
#pragma unroll
        for (int r = 0; r < 4; ++r) {
          const int row48 = mi * 16 + (lane >> 4) * 4 + r;
          if (row48 > 32) continue;
          const size_t Mrow = (row48 < 32) ? (size_t)(b * F_ + row48) : (size_t)(M_ROWS + b);
          const float v = acc[mi][r];
          const unsigned short h = f2bf(v);
          Mh[Mrow * 512 + col] = h;
          Ml[Mrow * 512 + col] = f2bf(v - bf2f(h));
        }
      __syncthreads();
    }
  }
}

// ---------------- Kernel 2: gathered dbuf MFMA GEMM (EXACT R7) --------------
__global__ __launch_bounds__(256) void gemm1(
    const unsigned short* __restrict__ Xhi, const unsigned short* __restrict__ Xlo,
    const unsigned short* __restrict__ Mh, const unsigned short* __restrict__ Ml,
    const unsigned short* __restrict__ Wthi, const unsigned short* __restrict__ Wtlo,
    const int* __restrict__ idx1, const float* __restrict__ b0,
    unsigned short* __restrict__ Hhi, unsigned short* __restrict__ Hlo) {
  __shared__ unsigned short lds[24576];  // 48 KB
  const int tid = threadIdx.x;
  const int lane = tid & 63;
  const int w = tid >> 6;
  const int wr = w >> 1, wc = w & 1;
  const int lr = lane & 15;
  const int kb = lane >> 4;
  const int swz = lr & 7;
  const int rsel = lane >> 3;
  const int cbs = ((lane & 7) ^ rsel) * 8;

  const int o = blockIdx.x;
  const int s = (o & 7) * 66 + (o >> 3);  // 528 = 8 XCDs * 66, bijective
  const int bmi = s >> 4;
  const int bni = s & 15;
  const int bm = bmi * 64;
  const int bn = bni * 32;

  int xrow[8];
  if (w < 2) {
#pragma unroll
    for (int i = 0; i < 8; ++i) {
      const int R = bm + rsel + 8 * i;
      if (bmi < 32) xrow[i] = (R >> 5) * 64 + idx1[R];
      else          xrow[i] = (R - M_ROWS) * 64;  // f0 row of batch
    }
  }
  const unsigned short* Xp = (w == 0) ? Xhi : Xlo;
  const unsigned short* Mp = (w == 0) ? Mh : Ml;
  const unsigned short* Wp = (w == 2) ? Wthi : Wtlo;
  const unsigned short* mbase = Mp + (size_t)(bm + rsel) * 512 + cbs;
  const unsigned short* wbase = Wp + (size_t)(bn + rsel) * KA + cbs;
  const int PB = (w == 0) ? 0 : (w == 1) ? 4096 : (w == 2) ? 8192 : 10240;

#define STAGE(KT, BUF)                                                        \
  {                                                                           \
    unsigned short* ldst = &lds[(BUF)*12288 + PB];                            \
    if (w < 2) {                                                              \
      if ((KT) < 8) {                                                         \
        const int co = (KT)*64 + cbs;                                         \
        _Pragma("unroll") for (int i = 0; i < 8; ++i)                         \
            GLOAD16(Xp + (size_t)xrow[i] * 512 + co, ldst + i * 512);         \
      } else {                                                                \
        const unsigned short* mb = mbase + ((KT)-8) * 64;                     \
        _Pragma("unroll") for (int i = 0; i < 8; ++i)                         \
            GLOAD16(mb + (size_t)i * 8 * 512, ldst + i * 512);                \
      }                                                                       \
    } else {                                                                  \
      const unsigned short* wb = wbase + (KT)*64;                             \
      _Pragma("unroll") for (int i = 0; i < 4; ++i)                           \
          GLOAD16(wb + (size_t)i * 8 * KA, ldst + i * 512);                   \
    }                                                                         \
  }

  f32x4 acc[2] = {};
  STAGE(0, 0);
  __syncthreads();

#define AFRAG(PL, ROW, CB) \
  (*(const bf16x8*)&lds[buf * 12288 + (PL)*4096 + (ROW)*64 + (((CB) ^ swz) * 8)])
#define BFRAG(PL, ROW, CB) \
  (*(const bf16x8*)&lds[buf * 12288 + 8192 + (PL)*2048 + (ROW)*64 + (((CB) ^ swz) * 8)])

  for (int kt = 0; kt < 16; ++kt) {
    const int buf = kt & 1;
    if (kt < 15) STAGE(kt + 1, buf ^ 1);
#pragma unroll
    for (int ks = 0; ks < 2; ++ks) {
      const int c = ks * 4 + kb;
      const bf16x8 Ah0 = AFRAG(0, wr * 32 + lr, c);
      const bf16x8 Ah1 = AFRAG(0, wr * 32 + 16 + lr, c);
      const bf16x8 Al0 = AFRAG(1, wr * 32 + lr, c);
      const bf16x8 Al1 = AFRAG(1, wr * 32 + 16 + lr, c);
      const bf16x8 Bh = BFRAG(0, wc * 16 + lr, c);
      const bf16x8 Bl = BFRAG(1, wc * 16 + lr, c);
      acc[0] = __builtin_amdgcn_mfma_f32_16x16x32_bf16(Ah0, Bh, acc[0], 0, 0, 0);
      acc[0] = __builtin_amdgcn_mfma_f32_16x16x32_bf16(Ah0, Bl, acc[0], 0, 0, 0);
      acc[0] = __builtin_amdgcn_mfma_f32_16x16x32_bf16(Al0, Bh, acc[0], 0, 0, 0);
      acc[1] = __builtin_amdgcn_mfma_f32_16x16x32_bf16(Ah1, Bh, acc[1], 0, 0, 0);
      acc[1] = __builtin_amdgcn_mfma_f32_16x16x32_bf16(Ah1, Bl, acc[1], 0, 0, 0);
      acc[1] = __builtin_amdgcn_mfma_f32_16x16x32_bf16(Al1, Bh, acc[1], 0, 0, 0);
    }
    __syncthreads();
  }
#undef AFRAG
#undef BFRAG
#undef STAGE

  const int col = bn + wc * 16 + lr;
  const float bias = b0[col];
  if (bmi < 32) {
    const int b = bmi * 2 + wr;
    float sum = 0.f;
#pragma unroll
    for (int mi = 0; mi < 2; ++mi)
#pragma unroll
      for (int r = 0; r < 4; ++r) sum += leaky(acc[mi][r] + bias);
    sum += __shfl_xor(sum, 16);
    sum += __shfl_xor(sum, 32);
    sum *= (1.0f / 32.0f);
    if (lane < 16) {
      const unsigned short h = f2bf(sum);
      Hhi[(size_t)b * KA + 512 + col] = h;
      Hlo[(size_t)b * KA + 512 + col] = f2bf(sum - bf2f(h));
    }
  } else {
#pragma unroll
    for (int mi = 0; mi < 2; ++mi)
#pragma unroll
      for (int r = 0; r < 4; ++r) {
        const int b = wr * 32 + mi * 16 + kb * 4 + r;
        const float v = leaky(acc[mi][r] + bias);
        const unsigned short h = f2bf(v);
        Hhi[(size_t)b * KA + col] = h;
        Hlo[(size_t)b * KA + col] = f2bf(v - bf2f(h));
      }
  }
}

// ---------------- Kernel 3: gemm2 + bias + reduce fused (EXACT R9) ----------
__global__ __launch_bounds__(512) void gemm2f(
    const unsigned short* __restrict__ Hhi, const unsigned short* __restrict__ Hlo,
    const unsigned short* __restrict__ Wthi, const unsigned short* __restrict__ Wtlo,
    const float* __restrict__ b1, float* __restrict__ out) {
  __shared__ float sacc[8][1088];
  const int tid = threadIdx.x;
  const int w = tid >> 6;
  const int lane = tid & 63;
  const int lr = lane & 15;
  const int kb = lane >> 4;
  const int n0 = blockIdx.x * 16;
  const int kc = w * 128;

  f32x4 acc[4] = {};
#pragma unroll
  for (int ks = 0; ks < 4; ++ks) {
    const int k = kc + ks * 32 + kb * 8;
    const bf16x8 Bh = *(const bf16x8*)(Wthi + (size_t)(n0 + lr) * KA + k);
    const bf16x8 Bl = *(const bf16x8*)(Wtlo + (size_t)(n0 + lr) * KA + k);
#pragma unroll
    for (int mi = 0; mi < 4; ++mi) {
      const bf16x8 Ah = *(const bf16x8*)(Hhi + (size_t)(mi * 16 + lr) * KA + k);
      const bf16x8 Al = *(const bf16x8*)(Hlo + (size_t)(mi * 16 + lr) * KA + k);
      acc[mi] = __builtin_amdgcn_mfma_f32_16x16x32_bf16(Ah, Bh, acc[mi], 0, 0, 0);
      acc[mi] = __builtin_amdgcn_mfma_f32_16x16x32_bf16(Ah, Bl, acc[mi], 0, 0, 0);
      acc[mi] = __builtin_amdgcn_mfma_f32_16x16x32_bf16(Al, Bh, acc[mi], 0, 0, 0);
    }
  }
#pragma unroll
  for (int mi = 0; mi < 4; ++mi)
#pragma unroll
    for (int r = 0; r < 4; ++r)
      sacc[w][(mi * 16 + kb * 4 + r) * 17 + lr] = acc[mi][r];
  __syncthreads();

#pragma unroll
  for (int q = 0; q < 2; ++q) {
    const int oid = tid * 2 + q;
    const int row = oid >> 4;
    const int col = oid & 15;
    float sv = b1[n0 + col];
#pragma unroll
    for (int w2 = 0; w2 < 8; ++w2) sv += sacc[w2][row * 17 + col];
    out[(size_t)row * H_ + n0 + col] = sv;
  }
}

extern "C" void kernel_launch(void* const* d_in, const int* in_sizes, int n_in,
                              void* d_out, int out_size, void* d_ws, size_t ws_size,
                              hipStream_t stream) {
  const float* x    = (const float*)d_in[0];
  const int*   idx1 = (const int*)d_in[1];
  const int*   idx2 = (const int*)d_in[2];
  const float* Wa0  = (const float*)d_in[3];
  const float* b0   = (const float*)d_in[4];
  const float* Ws0  = (const float*)d_in[5];
  const float* Wa1  = (const float*)d_in[6];
  const float* b1   = (const float*)d_in[7];
  const float* Ws1  = (const float*)d_in[8];
  float* out = (float*)d_out;

  unsigned short* wsu = (unsigned short*)d_ws;
  unsigned short* Xhi   = wsu;                          // 4096*512
  unsigned short* Xlo   = Xhi + (size_t)4096 * 512;
  unsigned short* Mh    = Xlo + (size_t)4096 * 512;     // 2112*512
  unsigned short* Ml    = Mh + (size_t)M2 * 512;
  unsigned short* W0thi = Ml + (size_t)M2 * 512;        // [512][1024] each
  unsigned short* W0tlo = W0thi + (size_t)H_ * KA;
  unsigned short* W1thi = W0tlo + (size_t)H_ * KA;
  unsigned short* W1tlo = W1thi + (size_t)H_ * KA;
  unsigned short* Hhi   = W1tlo + (size_t)H_ * KA;      // 64*1024 each
  unsigned short* Hlo   = Hhi + (size_t)B_ * KA;

  prep<<<576, 256, 0, stream>>>(x, idx1, idx2, Ws0, Wa0, Ws1, Wa1,
                                Xhi, Xlo, Mh, Ml, W0thi, W0tlo, W1thi, W1tlo);
  gemm1<<<528, 256, 0, stream>>>(Xhi, Xlo, Mh, Ml, W0thi, W0tlo,
                                 idx1, b0, Hhi, Hlo);
  gemm2f<<<32, 512, 0, stream>>>(Hhi, Hlo, W1thi, W1tlo, b1, out);
}

// Round 13
// 36.453 us; speedup vs baseline: 1.5599x; 1.2763x over previous
//
#include <hip/hip_runtime.h>
#include <hip/hip_bf16.h>

// Shapes
#define B_ 64
#define L_ 64
#define D_ 512
#define F_ 32
#define H_ 512
#define M_ROWS 2048
#define M2 2112
#define KA 1024

typedef __attribute__((ext_vector_type(8))) short bf16x8;
typedef __attribute__((ext_vector_type(4))) float f32x4;

__device__ __forceinline__ float leaky(float v) { return v > 0.0f ? v : 0.01f * v; }

__device__ __forceinline__ unsigned short f2bf(float v) {
  unsigned int b = __float_as_uint(v);
  unsigned int r = b + 0x7FFF + ((b >> 16) & 1);  // RNE
  return (unsigned short)(r >> 16);
}
__device__ __forceinline__ float bf2f(unsigned short h) {
  return __uint_as_float(((unsigned int)h) << 16);
}
__device__ __forceinline__ void cvt_store4(unsigned short* ph, unsigned short* pl, float4 v) {
  ushort4 h, l;
  h.x = f2bf(v.x); l.x = f2bf(v.x - bf2f(h.x));
  h.y = f2bf(v.y); l.y = f2bf(v.y - bf2f(h.y));
  h.z = f2bf(v.z); l.z = f2bf(v.z - bf2f(h.z));
  h.w = f2bf(v.w); l.w = f2bf(v.w - bf2f(h.w));
  *(ushort4*)ph = h;
  *(ushort4*)pl = l;
}

#define GLOAD16(GP, LP)                                              \
  __builtin_amdgcn_global_load_lds(                                  \
      (const __attribute__((address_space(1))) unsigned int*)(GP),   \
      (__attribute__((address_space(3))) unsigned int*)(LP), 16, 0, 0)

// ---------------- Kernel 1: prep (R7 phases; x-split regridded to 512) ------
// blocks [0,512):    x-split flat (4 float4/thread) -> Xhi/Xlo [4096][512]
// blocks [512,768):  w-split (EXACT R7 code, q = blk-512)
// blocks [768,1024): means (EXACT R7 code, q = blk-768)
__global__ __launch_bounds__(256) void prep(
    const float* __restrict__ x, const int* __restrict__ idx1,
    const int* __restrict__ idx2,
    const float* __restrict__ Ws0, const float* __restrict__ Wa0,
    const float* __restrict__ Ws1, const float* __restrict__ Wa1,
    unsigned short* __restrict__ Xhi, unsigned short* __restrict__ Xlo,
    unsigned short* __restrict__ Mh, unsigned short* __restrict__ Ml,
    unsigned short* __restrict__ W0thi, unsigned short* __restrict__ W0tlo,
    unsigned short* __restrict__ W1thi, unsigned short* __restrict__ W1tlo) {
  __shared__ __align__(16) char smem[33024];
  const int blk = blockIdx.x;
  const int t = threadIdx.x;

  if (blk < 512) {
    // x-split: 512 blocks x 256 thr x 4 float4 = 524288 float4 (byte-equal to R7)
    const int base = blk * 256 + t;
#pragma unroll
    for (int i = 0; i < 4; ++i) {
      const int f4 = base + i * 131072;
      const float4 v = *(const float4*)(x + (size_t)f4 * 4);
      cvt_store4(Xhi + (size_t)f4 * 4, Xlo + (size_t)f4 * 4, v);
    }
  } else if (blk < 768) {
    const int q = blk - 512;
    const int k0 = (q & 15) * 64;
    const int n0 = ((q >> 4) & 7) * 64;
    const int cat = q >> 7;
    float (*lt)[72] = (float(*)[72])smem;
    const float* src = (cat == 0)
        ? (k0 < 512 ? Ws0 + (size_t)k0 * H_ : Wa0 + (size_t)(k0 - 512) * H_)
        : (k0 < 512 ? Ws1 + (size_t)k0 * H_ : Wa1 + (size_t)(k0 - 512) * H_);
    unsigned short* dhi = (cat == 0) ? W0thi : W1thi;
    unsigned short* dlo = (cat == 0) ? W0tlo : W1tlo;
#pragma unroll
    for (int i = 0; i < 4; ++i) {
      const int idx4 = t + 256 * i;
      const int kl = idx4 >> 4;
      const int n4 = (idx4 & 15) * 4;
      *(float4*)&lt[kl][n4] = *(const float4*)(src + (size_t)kl * H_ + n0 + n4);
    }
    __syncthreads();
#pragma unroll
    for (int i = 0; i < 4; ++i) {
      const int idx4 = t + 256 * i;
      const int nl = idx4 >> 4;
      const int k4 = (idx4 & 15) * 4;
      ushort4 h, l;
      const float v0 = lt[k4 + 0][nl], v1 = lt[k4 + 1][nl];
      const float v2 = lt[k4 + 2][nl], v3 = lt[k4 + 3][nl];
      h.x = f2bf(v0); l.x = f2bf(v0 - bf2f(h.x));
      h.y = f2bf(v1); l.y = f2bf(v1 - bf2f(h.y));
      h.z = f2bf(v2); l.z = f2bf(v2 - bf2f(h.z));
      h.w = f2bf(v3); l.w = f2bf(v3 - bf2f(h.w));
      *(ushort4*)(dhi + (size_t)(n0 + nl) * KA + k0 + k4) = h;
      *(ushort4*)(dlo + (size_t)(n0 + nl) * KA + k0 + k4) = l;
    }
  } else {
    const int q = blk - 768;
    const int b = q >> 2;
    const int nt0 = (q & 3) * 2;
    unsigned int* cnt = (unsigned int*)smem;               // [33][64]
    unsigned short* Cm = (unsigned short*)(smem + 8448);   // [48][64]
    unsigned short* XTh = (unsigned short*)(smem + 14592); // [64][72]
    unsigned short* XTl = XTh + 64 * 72;
    const int lane = t & 63;
    const int w = t >> 6;
    const int lr = lane & 15;
    const int kb8 = (lane >> 4) * 8;

#pragma unroll
    for (int i = 0; i < 9; ++i) { const int p = t + 256 * i; if (p < 2112) cnt[p] = 0u; }
#pragma unroll
    for (int i = 0; i < 12; ++i) Cm[t + 256 * i] = 0;
    __syncthreads();
#pragma unroll
    for (int i = 0; i < 4; ++i) {
      const int j = t + 256 * i;
      atomicAdd(&cnt[(j >> 5) * 64 + idx2[(size_t)b * 1024 + j]], 1u);
    }
    if (t < 32) atomicAdd(&cnt[32 * 64 + idx1[b * F_ + t]], 1u);
    __syncthreads();
#pragma unroll
    for (int i = 0; i < 9; ++i) {
      const int p = t + 256 * i;
      if (p < 2112) Cm[p] = f2bf((float)cnt[p] * 0.03125f);
    }
    __syncthreads();
    bf16x8 Af[3][2];
#pragma unroll
    for (int mi = 0; mi < 3; ++mi)
#pragma unroll
      for (int kt = 0; kt < 2; ++kt)
        Af[mi][kt] = *(const bf16x8*)&Cm[(mi * 16 + lr) * 64 + kt * 32 + kb8];

#pragma unroll
    for (int tt = 0; tt < 2; ++tt) {
      const int nbase = (nt0 + tt) * 64;
#pragma unroll
      for (int i = 0; i < 4; ++i) {
        const int f4 = t + 256 * i;
        const int l = f4 >> 4;
        const int c4 = (f4 & 15) * 4;
        const float4 v = *(const float4*)(x + (size_t)b * (L_ * D_) + (size_t)l * D_ + nbase + c4);
        unsigned short h;
        h = f2bf(v.x); XTh[(c4 + 0) * 72 + l] = h; XTl[(c4 + 0) * 72 + l] = f2bf(v.x - bf2f(h));
        h = f2bf(v.y); XTh[(c4 + 1) * 72 + l] = h; XTl[(c4 + 1) * 72 + l] = f2bf(v.y - bf2f(h));
        h = f2bf(v.z); XTh[(c4 + 2) * 72 + l] = h; XTl[(c4 + 2) * 72 + l] = f2bf(v.z - bf2f(h));
        h = f2bf(v.w); XTh[(c4 + 3) * 72 + l] = h; XTl[(c4 + 3) * 72 + l] = f2bf(v.w - bf2f(h));
      }
      __syncthreads();
      f32x4 acc[3] = {};
#pragma unroll
      for (int kt = 0; kt < 2; ++kt) {
        const bf16x8 Bh = *(const bf16x8*)&XTh[(w * 16 + lr) * 72 + kt * 32 + kb8];
        const bf16x8 Bl = *(const bf16x8*)&XTl[(w * 16 + lr) * 72 + kt * 32 + kb8];
#pragma unroll
        for (int mi = 0; mi < 3; ++mi) {
          acc[mi] = __builtin_amdgcn_mfma_f32_16x16x32_bf16(Af[mi][kt], Bh, acc[mi], 0, 0, 0);
          acc[mi] = __builtin_amdgcn_mfma_f32_16x16x32_bf16(Af[mi][kt], Bl, acc[mi], 0, 0, 0);
        }
      }
      const int col = nbase + w * 16 + lr;
#pragma unroll
      for (int mi = 0; mi < 3; ++mi)
#pragma unroll
        for (int r = 0; r < 4; ++r) {
          const int row48 = mi * 16 + (lane >> 4) * 4 + r;
          if (row48 > 32) continue;
          const size_t Mrow = (row48 < 32) ? (size_t)(b * F_ + row48) : (size_t)(M_ROWS + b);
          const float v = acc[mi][r];
          const unsigned short h = f2bf(v);
          Mh[Mrow * 512 + col] = h;
          Ml[Mrow * 512 + col] = f2bf(v - bf2f(h));
        }
      __syncthreads();
    }
  }
}

// ---------------- Kernel 2: gathered dbuf MFMA GEMM (EXACT R7) --------------
__global__ __launch_bounds__(256) void gemm1(
    const unsigned short* __restrict__ Xhi, const unsigned short* __restrict__ Xlo,
    const unsigned short* __restrict__ Mh, const unsigned short* __restrict__ Ml,
    const unsigned short* __restrict__ Wthi, const unsigned short* __restrict__ Wtlo,
    const int* __restrict__ idx1, const float* __restrict__ b0,
    unsigned short* __restrict__ Hhi, unsigned short* __restrict__ Hlo) {
  __shared__ unsigned short lds[24576];  // 48 KB
  const int tid = threadIdx.x;
  const int lane = tid & 63;
  const int w = tid >> 6;
  const int wr = w >> 1, wc = w & 1;
  const int lr = lane & 15;
  const int kb = lane >> 4;
  const int swz = lr & 7;
  const int rsel = lane >> 3;
  const int cbs = ((lane & 7) ^ rsel) * 8;

  const int o = blockIdx.x;
  const int s = (o & 7) * 66 + (o >> 3);  // 528 = 8 XCDs * 66, bijective
  const int bmi = s >> 4;
  const int bni = s & 15;
  const int bm = bmi * 64;
  const int bn = bni * 32;

  int xrow[8];
  if (w < 2) {
#pragma unroll
    for (int i = 0; i < 8; ++i) {
      const int R = bm + rsel + 8 * i;
      if (bmi < 32) xrow[i] = (R >> 5) * 64 + idx1[R];
      else          xrow[i] = (R - M_ROWS) * 64;  // f0 row of batch
    }
  }
  const unsigned short* Xp = (w == 0) ? Xhi : Xlo;
  const unsigned short* Mp = (w == 0) ? Mh : Ml;
  const unsigned short* Wp = (w == 2) ? Wthi : Wtlo;
  const unsigned short* mbase = Mp + (size_t)(bm + rsel) * 512 + cbs;
  const unsigned short* wbase = Wp + (size_t)(bn + rsel) * KA + cbs;
  const int PB = (w == 0) ? 0 : (w == 1) ? 4096 : (w == 2) ? 8192 : 10240;

#define STAGE(KT, BUF)                                                        \
  {                                                                           \
    unsigned short* ldst = &lds[(BUF)*12288 + PB];                            \
    if (w < 2) {                                                              \
      if ((KT) < 8) {                                                         \
        const int co = (KT)*64 + cbs;                                         \
        _Pragma("unroll") for (int i = 0; i < 8; ++i)                         \
            GLOAD16(Xp + (size_t)xrow[i] * 512 + co, ldst + i * 512);         \
      } else {                                                                \
        const unsigned short* mb = mbase + ((KT)-8) * 64;                     \
        _Pragma("unroll") for (int i = 0; i < 8; ++i)                         \
            GLOAD16(mb + (size_t)i * 8 * 512, ldst + i * 512);                \
      }                                                                       \
    } else {                                                                  \
      const unsigned short* wb = wbase + (KT)*64;                             \
      _Pragma("unroll") for (int i = 0; i < 4; ++i)                           \
          GLOAD16(wb + (size_t)i * 8 * KA, ldst + i * 512);                   \
    }                                                                         \
  }

  f32x4 acc[2] = {};
  STAGE(0, 0);
  __syncthreads();

#define AFRAG(PL, ROW, CB) \
  (*(const bf16x8*)&lds[buf * 12288 + (PL)*4096 + (ROW)*64 + (((CB) ^ swz) * 8)])
#define BFRAG(PL, ROW, CB) \
  (*(const bf16x8*)&lds[buf * 12288 + 8192 + (PL)*2048 + (ROW)*64 + (((CB) ^ swz) * 8)])

  for (int kt = 0; kt < 16; ++kt) {
    const int buf = kt & 1;
    if (kt < 15) STAGE(kt + 1, buf ^ 1);
#pragma unroll
    for (int ks = 0; ks < 2; ++ks) {
      const int c = ks * 4 + kb;
      const bf16x8 Ah0 = AFRAG(0, wr * 32 + lr, c);
      const bf16x8 Ah1 = AFRAG(0, wr * 32 + 16 + lr, c);
      const bf16x8 Al0 = AFRAG(1, wr * 32 + lr, c);
      const bf16x8 Al1 = AFRAG(1, wr * 32 + 16 + lr, c);
      const bf16x8 Bh = BFRAG(0, wc * 16 + lr, c);
      const bf16x8 Bl = BFRAG(1, wc * 16 + lr, c);
      acc[0] = __builtin_amdgcn_mfma_f32_16x16x32_bf16(Ah0, Bh, acc[0], 0, 0, 0);
      acc[0] = __builtin_amdgcn_mfma_f32_16x16x32_bf16(Ah0, Bl, acc[0], 0, 0, 0);
      acc[0] = __builtin_amdgcn_mfma_f32_16x16x32_bf16(Al0, Bh, acc[0], 0, 0, 0);
      acc[1] = __builtin_amdgcn_mfma_f32_16x16x32_bf16(Ah1, Bh, acc[1], 0, 0, 0);
      acc[1] = __builtin_amdgcn_mfma_f32_16x16x32_bf16(Ah1, Bl, acc[1], 0, 0, 0);
      acc[1] = __builtin_amdgcn_mfma_f32_16x16x32_bf16(Al1, Bh, acc[1], 0, 0, 0);
    }
    __syncthreads();
  }
#undef AFRAG
#undef BFRAG
#undef STAGE

  const int col = bn + wc * 16 + lr;
  const float bias = b0[col];
  if (bmi < 32) {
    const int b = bmi * 2 + wr;
    float sum = 0.f;
#pragma unroll
    for (int mi = 0; mi < 2; ++mi)
#pragma unroll
      for (int r = 0; r < 4; ++r) sum += leaky(acc[mi][r] + bias);
    sum += __shfl_xor(sum, 16);
    sum += __shfl_xor(sum, 32);
    sum *= (1.0f / 32.0f);
    if (lane < 16) {
      const unsigned short h = f2bf(sum);
      Hhi[(size_t)b * KA + 512 + col] = h;
      Hlo[(size_t)b * KA + 512 + col] = f2bf(sum - bf2f(h));
    }
  } else {
#pragma unroll
    for (int mi = 0; mi < 2; ++mi)
#pragma unroll
      for (int r = 0; r < 4; ++r) {
        const int b = wr * 32 + mi * 16 + kb * 4 + r;
        const float v = leaky(acc[mi][r] + bias);
        const unsigned short h = f2bf(v);
        Hhi[(size_t)b * KA + col] = h;
        Hlo[(size_t)b * KA + col] = f2bf(v - bf2f(h));
      }
  }
}

// ---------------- Kernel 3: gemm2 split-K partials (EXACT R7) ---------------
__global__ __launch_bounds__(256) void gemm2(
    const unsigned short* __restrict__ Hhi, const unsigned short* __restrict__ Hlo,
    const unsigned short* __restrict__ Wthi, const unsigned short* __restrict__ Wtlo,
    float* __restrict__ part) {
  __shared__ float sacc[256][17];
  const int tid = threadIdx.x;
  const int w = tid >> 6;
  const int lane = tid & 63;
  const int lr = lane & 15;
  const int kb = lane >> 4;
  const int n0 = blockIdx.x * 16;
  const int kc = blockIdx.y * 128;

  f32x4 acc[4] = {};
  const int k = kc + w * 32 + kb * 8;
  const bf16x8 Bh = *(const bf16x8*)(Wthi + (size_t)(n0 + lr) * KA + k);
  const bf16x8 Bl = *(const bf16x8*)(Wtlo + (size_t)(n0 + lr) * KA + k);
#pragma unroll
  for (int mi = 0; mi < 4; ++mi) {
    const bf16x8 Ah = *(const bf16x8*)(Hhi + (size_t)(mi * 16 + lr) * KA + k);
    const bf16x8 Al = *(const bf16x8*)(Hlo + (size_t)(mi * 16 + lr) * KA + k);
    acc[mi] = __builtin_amdgcn_mfma_f32_16x16x32_bf16(Ah, Bh, acc[mi], 0, 0, 0);
    acc[mi] = __builtin_amdgcn_mfma_f32_16x16x32_bf16(Ah, Bl, acc[mi], 0, 0, 0);
    acc[mi] = __builtin_amdgcn_mfma_f32_16x16x32_bf16(Al, Bh, acc[mi], 0, 0, 0);
  }
#pragma unroll
  for (int mi = 0; mi < 4; ++mi)
#pragma unroll
    for (int r = 0; r < 4; ++r)
      sacc[((w * 4 + mi) * 4 + kb) * 4 + r][lr] = acc[mi][r];
  __syncthreads();

  const int lr2 = tid & 15;
  const int rg = tid >> 4;
  float* pp = part + (size_t)blockIdx.y * (B_ * H_);
#pragma unroll
  for (int q = 0; q < 4; ++q) {
    const int row = rg * 4 + q;
    const int mi = row >> 4, kb2 = (row >> 2) & 3, r = row & 3;
    float sv = 0.f;
#pragma unroll
    for (int w2 = 0; w2 < 4; ++w2)
      sv += sacc[((w2 * 4 + mi) * 4 + kb2) * 4 + r][lr2];
    pp[(size_t)row * H_ + n0 + lr2] = sv;
  }
}

// ---------------- Kernel 4: out = sum_k part + b1 (EXACT R7) ----------------
__global__ __launch_bounds__(256) void reduce_out(
    const float* __restrict__ part, const float* __restrict__ b1,
    float* __restrict__ out) {
  const int idx = blockIdx.x * 256 + threadIdx.x;
  const int c4 = (idx & 127) * 4;
  const size_t off = (size_t)(idx >> 7) * H_ + c4;
  float4 s = *(const float4*)(b1 + c4);
#pragma unroll
  for (int ky = 0; ky < 8; ++ky) {
    const float4 p = *(const float4*)(part + (size_t)ky * (B_ * H_) + off);
    s.x += p.x; s.y += p.y; s.z += p.z; s.w += p.w;
  }
  *(float4*)(out + off) = s;
}

extern "C" void kernel_launch(void* const* d_in, const int* in_sizes, int n_in,
                              void* d_out, int out_size, void* d_ws, size_t ws_size,
                              hipStream_t stream) {
  const float* x    = (const float*)d_in[0];
  const int*   idx1 = (const int*)d_in[1];
  const int*   idx2 = (const int*)d_in[2];
  const float* Wa0  = (const float*)d_in[3];
  const float* b0   = (const float*)d_in[4];
  const float* Ws0  = (const float*)d_in[5];
  const float* Wa1  = (const float*)d_in[6];
  const float* b1   = (const float*)d_in[7];
  const float* Ws1  = (const float*)d_in[8];
  float* out = (float*)d_out;

  unsigned short* wsu = (unsigned short*)d_ws;
  unsigned short* Xhi   = wsu;                          // 4096*512
  unsigned short* Xlo   = Xhi + (size_t)4096 * 512;
  unsigned short* Mh    = Xlo + (size_t)4096 * 512;     // 2112*512
  unsigned short* Ml    = Mh + (size_t)M2 * 512;
  unsigned short* W0thi = Ml + (size_t)M2 * 512;        // [512][1024] each
  unsigned short* W0tlo = W0thi + (size_t)H_ * KA;
  unsigned short* W1thi = W0tlo + (size_t)H_ * KA;
  unsigned short* W1tlo = W1thi + (size_t)H_ * KA;
  unsigned short* Hhi   = W1tlo + (size_t)H_ * KA;      // 64*1024 each
  unsigned short* Hlo   = Hhi + (size_t)B_ * KA;
  float* part = (float*)(Hlo + (size_t)B_ * KA);        // 8*64*512 fp32

  prep<<<1024, 256, 0, stream>>>(x, idx1, idx2, Ws0, Wa0, Ws1, Wa1,
                                 Xhi, Xlo, Mh, Ml, W0thi, W0tlo, W1thi, W1tlo);
  gemm1<<<528, 256, 0, stream>>>(Xhi, Xlo, Mh, Ml, W0thi, W0tlo,
                                 idx1, b0, Hhi, Hlo);
  gemm2<<<dim3(32, 8), 256, 0, stream>>>(Hhi, Hlo, W1thi, W1tlo, part);
  reduce_out<<<32, 256, 0, stream>>>(part, b1, out);
}